// Round 3
// baseline (307.508 us; speedup 1.0000x reference)
//
#include <hip/hip_runtime.h>
#include <hip/hip_bf16.h>
#include <cstdint>

// DifferentiableILP on MI355X (gfx950).
// A = softmax(rule_weights[:,0,:]); 3x: facts = max(facts, colmax(A @ facts)).
// Columns independent -> each block owns a 64-col stripe; ft immutable in LDS,
// running col-max folded into the B fragment at load time (packed u16 max).
//
// R5 changes vs R4 (ilp 149.8us, MfmaUtil 29%, Occ 20%, conflicts 3.44M):
//  - 512-thread blocks, 64 rows/wave: acc[2][2]=64 AGPR -> total regs <=~128
//    -> 4 waves/SIMD (16 waves/CU) instead of 2 (R4 was 232 regs -> 2/SIMD).
//    TLP now covers A-load L2 latency exposed by the shorter 32x32 k-step.
//  - ft stored FRAGMENT-LINEAR: chunk ftB[g][c] at (g*64+c)*16B, g=kt2*2+half.
//    GEMM B-reads are 256B-contiguous per 16-lane quarter -> zero bank
//    conflicts, no XOR swizzle, ct2 folded into ds_read immediate offset.
//  - stage/epilogue: c=tid&63 scalar global accesses (256B/inst coalesced),
//    LDS side perfectly linear b128 -> zero conflicts there too.
//  - A kt2=0 prologue issued BEFORE the stage barrier (overlaps staging).

typedef __attribute__((ext_vector_type(8))) short bf16x8;   // 8 bf16 = 4 VGPRs
typedef __attribute__((ext_vector_type(8))) unsigned short u16x8;
typedef __attribute__((ext_vector_type(16))) float f32x16;  // 32x32 accumulator
typedef unsigned short ushort_t;
typedef unsigned int uint32;

#define PDIM 512
#define CDIM 65536
#define NT   64      // columns per block
#define WAVES 8

__device__ __forceinline__ ushort_t f2bf(float x) {          // RNE float->bf16
    uint32 u = __float_as_uint(x);
    return (ushort_t)((u + 0x7fffu + ((u >> 16) & 1u)) >> 16);
}
__device__ __forceinline__ float bf2f(uint32 bits) { return __uint_as_float(bits << 16); }

// packed max(v, splat(mu)) in the u16 domain (valid: all values are nonneg bf16)
__device__ __forceinline__ bf16x8 pkmax8(bf16x8 v, ushort_t mu) {
    u16x8 a = __builtin_bit_cast(u16x8, v);
    const u16x8 mb = {mu, mu, mu, mu, mu, mu, mu, mu};
    a = __builtin_elementwise_max(a, mb);
    return __builtin_bit_cast(bf16x8, a);
}

// ---- phase 1: softmax row r, packed fragment-linear for 32x32x16 MFMA.
// chunk idx16 = (kt2*16 + (r>>5))*64 + half*32 + (r&31) holds
// A[r][kt2*16 + half*8 .. +7] as 8 bf16.
__global__ __launch_bounds__(64) void softmax_pack(const float* __restrict__ rw,
                                                   ushort_t* __restrict__ Apk) {
    const int r  = blockIdx.x;
    const int ln = threadIdx.x;
    const float* row = rw + r * PDIM;
    float4 x0 = *(const float4*)(row + ln * 8);
    float4 x1 = *(const float4*)(row + ln * 8 + 4);
    float v[8] = {x0.x, x0.y, x0.z, x0.w, x1.x, x1.y, x1.z, x1.w};

    float mx = -1e30f;
    #pragma unroll
    for (int i = 0; i < 8; ++i) mx = fmaxf(mx, v[i]);
    #pragma unroll
    for (int d = 1; d < 64; d <<= 1) mx = fmaxf(mx, __shfl_xor(mx, d, 64));
    float s = 0.f;
    #pragma unroll
    for (int i = 0; i < 8; ++i) { v[i] = __expf(v[i] - mx); s += v[i]; }
    #pragma unroll
    for (int d = 1; d < 64; d <<= 1) s += __shfl_xor(s, d, 64);
    const float inv = 1.f / s;

    ushort_t o[8];
    #pragma unroll
    for (int i = 0; i < 8; ++i) o[i] = f2bf(v[i] * inv);
    // lane holds k-chunk kh = ln (k = ln*8..+7): kt2 = ln>>1, half = ln&1
    const int idx16 = ((ln >> 1) * 16 + (r >> 5)) * 64 + ((ln & 1) << 5) + (r & 31);
    *(int4*)(Apk + idx16 * 8) = *(const int4*)o;
}

// ---- phase 2: per-64-column stripe, fused multi-iteration fixpoint.
// LDS ftB: 16B chunk (g, c) at element (g*64 + c)*8, g = p-granule (p=g*8..+7).
__global__ __launch_bounds__(512, 4) void ilp_kernel(
        const float* __restrict__ facts,
        const ushort_t* __restrict__ Apk,
        const int* __restrict__ n_iter_p,
        float* __restrict__ out) {
    __shared__ ushort_t ft[64 * NT * 8];   // 65536 B
    __shared__ float wred[2][WAVES][NT];   // 4096 B: per-wave colmax partials, dbuf
    __shared__ float mfin[NT];             // 256 B: final column max for epilogue

    const int tid  = threadIdx.x;
    const int wave = tid >> 6;
    const int lane = tid & 63;
    const int l31  = lane & 31;
    const int half = lane >> 5;
    const int c0   = blockIdx.x * NT;

    int n_iter = *n_iter_p;                // issue scalar load early
    n_iter = n_iter < 0 ? 0 : (n_iter > 8 ? 8 : n_iter);

    // ---- stage: ftB[g][c] = bf16(facts[g*8..+7][c0+c]); linear b128 writes
    {
        const int c = tid & 63;
        #pragma unroll 2
        for (int s = 0; s < 8; ++s) {
            const int g = wave * 8 + s;
            ushort_t gb[8];
            #pragma unroll
            for (int i = 0; i < 8; ++i)
                gb[i] = f2bf(facts[(g * 8 + i) * CDIM + c0 + c]);
            *(int4*)(&ft[(g * 64 + c) * 8]) = *(const int4*)gb;
        }
    }

    // A prologue (kt2=0) issued before the barrier: overlaps staging.
    // wave owns rows wave*64 + rt2*32 + l31; chunk base = wave*128 + half*32 + l31.
    const ushort_t* abase = Apk + (wave * 128 + half * 32 + l31) * 8;
    bf16x8 aF[2][2], bR[2][2];
    aF[0][0] = *(const bf16x8*)(abase);
    aF[0][1] = *(const bf16x8*)(abase + 512);

    __syncthreads();

    // B element base: ((kt2*2 + half)*64 + ct2*32 + l31)*8 = bbase + kt2*1024 + ct2*256
    const int bbase = (half * 64 + l31) * 8;
    bR[0][0] = *(const bf16x8*)(&ft[bbase]);
    bR[0][1] = *(const bf16x8*)(&ft[bbase + 256]);

    ushort_t ml[2] = {0, 0};               // running colmax, bf16 bits
    float    mf[2] = {0.f, 0.f};           // running colmax, f32

    #pragma unroll 1
    for (int it = 0; it < n_iter; ++it) {
        f32x16 acc[2][2];
        #pragma unroll
        for (int rt2 = 0; rt2 < 2; ++rt2)
            #pragma unroll
            for (int ct2 = 0; ct2 < 2; ++ct2)
                #pragma unroll
                for (int e = 0; e < 16; ++e) acc[rt2][ct2][e] = 0.f;

        #pragma unroll 2
        for (int kt2 = 0; kt2 < 32; ++kt2) {
            const int cur = kt2 & 1, nxt = cur ^ 1;
            const int ktn = (kt2 + 1) & 31;         // kt2=31 wraps: feeds next iter
            {   // prefetch next A frags (L2-resident Apk)
                const ushort_t* ap = abase + ktn * 8192;
                aF[nxt][0] = *(const bf16x8*)(ap);
                aF[nxt][1] = *(const bf16x8*)(ap + 512);
            }
            {   // prefetch next raw B frags (conflict-free linear ds_read_b128)
                const int bo = bbase + ktn * 1024;
                bR[nxt][0] = *(const bf16x8*)(&ft[bo]);
                bR[nxt][1] = *(const bf16x8*)(&ft[bo + 256]);
            }
            __builtin_amdgcn_s_setprio(1);
            #pragma unroll
            for (int ct2 = 0; ct2 < 2; ++ct2) {
                // fold running colmax into cur B (loaded a full k-step ago: ready)
                const bf16x8 bC = pkmax8(bR[cur][ct2], ml[ct2]);
                acc[0][ct2] = __builtin_amdgcn_mfma_f32_32x32x16_bf16(
                    aF[cur][0], bC, acc[0][ct2], 0, 0, 0);
                acc[1][ct2] = __builtin_amdgcn_mfma_f32_32x32x16_bf16(
                    aF[cur][1], bC, acc[1][ct2], 0, 0, 0);
            }
            __builtin_amdgcn_s_setprio(0);
        }

        // ---- colmax fold (D: col=lane&31; row identity irrelevant for colmax)
        float mx[2];
        #pragma unroll
        for (int ct2 = 0; ct2 < 2; ++ct2) {
            float m0 = -1e30f;
            #pragma unroll
            for (int rt2 = 0; rt2 < 2; ++rt2)
                #pragma unroll
                for (int e = 0; e < 16; ++e) m0 = fmaxf(m0, acc[rt2][ct2][e]);
            m0 = fmaxf(m0, __shfl_xor(m0, 32, 64));
            mx[ct2] = m0;
        }
        const int buf = it & 1;
        if (half == 0) {
            #pragma unroll
            for (int ct2 = 0; ct2 < 2; ++ct2) wred[buf][wave][ct2 * 32 + l31] = mx[ct2];
        }
        __syncthreads();
        #pragma unroll
        for (int ct2 = 0; ct2 < 2; ++ct2) {
            const int c = ct2 * 32 + l31;
            float m = wred[buf][0][c];
            #pragma unroll
            for (int w = 1; w < WAVES; ++w) m = fmaxf(m, wred[buf][w][c]);
            mf[ct2] = fmaxf(mf[ct2], m);    // monotone guard vs bf16 wobble
            ml[ct2] = f2bf(mf[ct2]);
        }
        // no second barrier: wred double-buffered (next write to this buf is
        // beyond the NEXT iteration's barrier, after all reads above).
    }

    // ---- publish final m per column for epilogue layout
    if (wave == 0 && half == 0) {
        mfin[l31]      = mf[0];
        mfin[32 + l31] = mf[1];
    }
    __syncthreads();

    // ---- epilogue: out = max(ft, m_final); linear b128 LDS reads, 256B stores
    {
        const int c = tid & 63;
        const float m = mfin[c];
        #pragma unroll 2
        for (int s = 0; s < 8; ++s) {
            const int g = wave * 8 + s;
            ushort_t gb[8];
            *(int4*)gb = *(const int4*)(&ft[(g * 64 + c) * 8]);
            #pragma unroll
            for (int i = 0; i < 8; ++i)
                out[(g * 8 + i) * CDIM + c0 + c] = fmaxf(bf2f(gb[i]), m);
        }
    }
}

extern "C" void kernel_launch(void* const* d_in, const int* in_sizes, int n_in,
                              void* d_out, int out_size, void* d_ws, size_t ws_size,
                              hipStream_t stream) {
    const float* facts    = (const float*)d_in[0];       // [512, 65536] fp32
    const float* rw       = (const float*)d_in[1];       // [512, 1, 512] fp32
    const int*   n_iter_p = (const int*)d_in[2];         // scalar 3
    float* out = (float*)d_out;

    ushort_t* Apk = (ushort_t*)d_ws;                     // 512 KB

    softmax_pack<<<PDIM, 64, 0, stream>>>(rw, Apk);
    ilp_kernel<<<CDIM / NT, 512, 0, stream>>>(facts, Apk, n_iter_p, out);
}